// Round 7
// baseline (154.635 us; speedup 1.0000x reference)
//
#include <hip/hip_runtime.h>
#include <hip/hip_bf16.h>
#include <stdint.h>

#define NTEST 4096
#define NTRAIN 16384
#define DIM 128
#define KEXP 128   // pure hi.hi bf16 (norms exact fp32)

typedef __attribute__((ext_vector_type(8))) short short8;
typedef __attribute__((ext_vector_type(16))) float float16v;

static __device__ __forceinline__ unsigned short f32_to_bf16_rne(float f) {
    union { float f; uint32_t u; } v; v.f = f;
    uint32_t u = v.u;
    uint32_t r = u + 0x7FFFu + ((u >> 16) & 1u);
    return (unsigned short)(r >> 16);
}

// ---- Kernel 1: per-column partial sums for std (coalesced) + zero out ----
__global__ void col_stats_partial(const float* __restrict__ train,
                                  float* __restrict__ psum, float* __restrict__ psumsq,
                                  float* __restrict__ out) {
    int b = blockIdx.x;       // 128 blocks x 128 rows each
    int t = threadIdx.x;      // 256
    if (b < 16) out[b * 256 + t] = 0.f;   // zero output (re-poisoned each call)
    int col = t & 127;
    int rh = t >> 7;          // 0/1
    float s = 0.f, ss = 0.f;
    int row0 = b * 128;
    for (int r = rh; r < 128; r += 2) {
        float x = train[(size_t)(row0 + r) * DIM + col];
        s += x; ss += x * x;
    }
    __shared__ float sh_s[256], sh_ss[256];
    sh_s[t] = s; sh_ss[t] = ss;
    __syncthreads();
    if (rh == 0) {
        psum[b * DIM + col]   = sh_s[col] + sh_s[col + 128];
        psumsq[b * DIM + col] = sh_ss[col] + sh_ss[col + 128];
    }
}

// ---- Kernel 2: bandwidth + Z scalars ----
__global__ void bandwidth_kernel(const float* __restrict__ psum, const float* __restrict__ psumsq,
                                 float* __restrict__ inv_bw, float* __restrict__ scalars) {
    int t = threadIdx.x;      // 256
    int c = t & 127;
    int h = t >> 7;
    float s = 0.f, ss = 0.f;
    for (int b = h * 64; b < h * 64 + 64; ++b) { s += psum[b * DIM + c]; ss += psumsq[b * DIM + c]; }
    __shared__ float S[256], SS[256], sh[128];
    S[t] = s; SS[t] = ss;
    __syncthreads();
    if (h == 0) {
        s = S[c] + S[c + 128]; ss = SS[c] + SS[c + 128];
        float n = (float)NTRAIN;
        float var = (ss - s * s / n) / (n - 1.0f);
        float sd = fmaxf(sqrtf(var), 0.01f);
        float bw = 1.06f * sd * expf(-logf(n) / (float)(4 + DIM));
        bw = fminf(bw, 0.49f);
        inv_bw[c] = 1.0f / bw;
        sh[c] = logf(bw);
    }
    __syncthreads();
    for (int off = 64; off > 0; off >>= 1) {
        if (t < off) sh[t] += sh[t + off];
        __syncthreads();
    }
    if (t == 0) {
        float Z = 0.5f * (float)DIM * logf(2.0f * 3.14159265358979323846f) + sh[0] + logf((float)NTRAIN);
        scalars[0] = -0.5f / Z;   // term = exp(scale*sq - 1)
    }
}

// ---- Kernel 3: train rows: scale, bf16 hi, exact row norms ----
__global__ void expand_train(const float* __restrict__ train, const float* __restrict__ inv_bw,
                             unsigned short* __restrict__ Be, float* __restrict__ rnorm) {
    int t = threadIdx.x;
    int r = blockIdx.x * 2 + (t >> 7);    // 0..NTRAIN-1
    int k = t & 127;
    float x = train[(size_t)r * DIM + k] * inv_bw[k];
    Be[(size_t)r * KEXP + k] = f32_to_bf16_rne(x);
    float nv = x * x;   // exact fp32 norm
    #pragma unroll
    for (int off = 32; off > 0; off >>= 1) nv += __shfl_xor(nv, off, 64);
    __shared__ float sh[4];
    if ((t & 63) == 0) sh[t >> 6] = nv;
    __syncthreads();
    if (k == 0) rnorm[r] = sh[(t >> 6)] + sh[(t >> 6) + 1];
}

// ---- Kernel 4: 64x128-tile GEMM (32x32x16), 3 blocks/CU, folded exp2 epilogue ----
__global__ __launch_bounds__(256, 3) void kde_main(
    const float* __restrict__ test, const unsigned short* __restrict__ Be,
    const float* __restrict__ inv_bw, const float* __restrict__ rnorm,
    const float* __restrict__ scalars, float* __restrict__ out) {

    __shared__ __align__(16) unsigned short As[64 * 128];     // 16 KB swizzled
    __shared__ __align__(16) unsigned short Bs[2][128 * 64];  // 2 x 16 KB
    __shared__ float tn_lds[64];

    const int t = threadIdx.x;
    const int m0 = blockIdx.x * 64;      // 64 m-blocks
    const int grp = blockIdx.y;          // 16 n-groups x 8 tiles of 128
    const int wave = t >> 6;             // wn: 0..3 (n-subtile of 32)
    const int lane = t & 63;
    const int col = lane & 31;           // operand row (m or n), C/D col
    const int half = lane >> 5;          // k-half; C/D row-group

    // ---- prefetch B segment 0 first ----
    {
        int n00 = grp * 8 * 128;
        #pragma unroll
        for (int rr = 0; rr < 4; ++rr) {
            int c = t + rr * 256;             // 0..1023 16B chunks
            int r = c >> 3;
            int p = (c & 7) ^ (r & 7);        // inverse swizzle on global side
            const unsigned short* gb = Be + (size_t)(n00 + r) * KEXP + p * 8;
            __builtin_amdgcn_global_load_lds((const __attribute__((address_space(1))) void*)gb,
                (__attribute__((address_space(3))) void*)(Bs[0] + c * 8), 16, 0, 0);
        }
    }

    // ---- build A (bf16 of test*inv_bw) swizzled in LDS + exact tnorm ----
    {
        int p = t & 15;                       // 16B chunk within row
        float4 w0 = *(const float4*)(inv_bw + p * 8);
        float4 w1 = *(const float4*)(inv_bw + p * 8 + 4);
        #pragma unroll
        for (int rr = 0; rr < 4; ++rr) {
            int row = (t >> 4) + rr * 16;     // 0..63
            const float* src = test + (size_t)(m0 + row) * DIM + p * 8;
            float4 v0 = *(const float4*)(src);
            float4 v1 = *(const float4*)(src + 4);
            v0.x *= w0.x; v0.y *= w0.y; v0.z *= w0.z; v0.w *= w0.w;
            v1.x *= w1.x; v1.y *= w1.y; v1.z *= w1.z; v1.w *= w1.w;
            short8 hv;
            hv[0] = (short)f32_to_bf16_rne(v0.x); hv[1] = (short)f32_to_bf16_rne(v0.y);
            hv[2] = (short)f32_to_bf16_rne(v0.z); hv[3] = (short)f32_to_bf16_rne(v0.w);
            hv[4] = (short)f32_to_bf16_rne(v1.x); hv[5] = (short)f32_to_bf16_rne(v1.y);
            hv[6] = (short)f32_to_bf16_rne(v1.z); hv[7] = (short)f32_to_bf16_rne(v1.w);
            int pp = p ^ (row & 7);
            *(short8*)(As + row * 128 + pp * 8) = hv;
            float nv = v0.x*v0.x + v0.y*v0.y + v0.z*v0.z + v0.w*v0.w
                     + v1.x*v1.x + v1.y*v1.y + v1.z*v1.z + v1.w*v1.w;
            #pragma unroll
            for (int off = 1; off < 16; off <<= 1) nv += __shfl_xor(nv, off, 16);
            if ((t & 15) == 0) tn_lds[row] = nv;
        }
    }
    __syncthreads();   // A + tnorm visible; B0 drained

    // folded epilogue constants: term = exp2( K2*d + (S1*(c0+rn) + C1) )
    const float scale = scalars[0];
    const float L2E = 1.44269504f;
    const float S1 = scale * L2E;
    const float K2 = -2.0f * scale * L2E;
    const float C1 = -L2E;

    float pc[2][16];
    #pragma unroll
    for (int tm = 0; tm < 2; ++tm)
        #pragma unroll
        for (int g = 0; g < 16; ++g) {
            int rowi = tm * 32 + (g & 3) + 8 * (g >> 2) + 4 * half;
            pc[tm][g] = fmaf(S1, tn_lds[rowi], C1);
        }

    int abase[2], arx[2];
    #pragma unroll
    for (int tm = 0; tm < 2; ++tm) {
        int rA = tm * 32 + col;
        abase[tm] = rA * 128;
        arx[tm] = rA & 7;
    }
    const int rB = wave * 32 + col;
    const int bbase = rB * 64;
    const int brx = rB & 7;

    float rs[2][16];
    #pragma unroll
    for (int tm = 0; tm < 2; ++tm)
        #pragma unroll
        for (int g = 0; g < 16; ++g) rs[tm][g] = 0.f;

    float16v acc[2];
    float pn = 0.f;

    // ---- 16 segments: 8 n-tiles x 2 K-chunks (KC=64) ----
    for (int s = 0; s < 16; ++s) {
        int buf = s & 1;
        if (s < 15) {   // prefetch next segment into other buffer
            int j2 = (s + 1) >> 1;
            int kc2 = ((s + 1) & 1) * 64;
            int n0j = (grp * 8 + j2) * 128;
            #pragma unroll
            for (int rr = 0; rr < 4; ++rr) {
                int c = t + rr * 256;
                int r = c >> 3;
                int p = (c & 7) ^ (r & 7);
                const unsigned short* gb = Be + (size_t)(n0j + r) * KEXP + kc2 + p * 8;
                __builtin_amdgcn_global_load_lds((const __attribute__((address_space(1))) void*)gb,
                    (__attribute__((address_space(3))) void*)(Bs[buf ^ 1] + c * 8), 16, 0, 0);
            }
        }
        if ((s & 1) == 0) {   // new n-tile: rnorm + zero acc
            int n0j = (grp * 8 + (s >> 1)) * 128;
            pn = S1 * rnorm[n0j + rB];
            acc[0] = (float16v)(0.f);
            acc[1] = (float16v)(0.f);
        }
        #pragma unroll
        for (int ks = 0; ks < 4; ++ks) {
            int kta = (s & 1) * 4 + ks;       // global K chunk-pair
            short8 af0 = *(const short8*)(As + abase[0] + (((kta * 2 + half) ^ arx[0]) << 3));
            short8 af1 = *(const short8*)(As + abase[1] + (((kta * 2 + half) ^ arx[1]) << 3));
            short8 bf  = *(const short8*)(Bs[buf] + bbase + (((ks * 2 + half) ^ brx) << 3));
            acc[0] = __builtin_amdgcn_mfma_f32_32x32x16_bf16(af0, bf, acc[0], 0, 0, 0);
            acc[1] = __builtin_amdgcn_mfma_f32_32x32x16_bf16(af1, bf, acc[1], 0, 0, 0);
        }
        if ((s & 1) == 1) {   // n-tile done: folded exp2 epilogue
            #pragma unroll
            for (int tm = 0; tm < 2; ++tm)
                #pragma unroll
                for (int g = 0; g < 16; ++g)
                    rs[tm][g] += exp2f(fmaf(K2, acc[tm][g], pc[tm][g] + pn));
        }
        __syncthreads();
    }

    // ---- final: reduce across 32 cols + atomics ----
    #pragma unroll
    for (int tm = 0; tm < 2; ++tm) {
        #pragma unroll
        for (int g = 0; g < 16; ++g) {
            float v = rs[tm][g];
            #pragma unroll
            for (int off = 1; off < 32; off <<= 1)
                v += __shfl_xor(v, off, 64);   // offs 1..16: stays within 32-lane half
            if (col == 0) {
                int rowi = tm * 32 + (g & 3) + 8 * (g >> 2) + 4 * half;
                atomicAdd(&out[m0 + rowi], v);
            }
        }
    }
}

extern "C" void kernel_launch(void* const* d_in, const int* in_sizes, int n_in,
                              void* d_out, int out_size, void* d_ws, size_t ws_size,
                              hipStream_t stream) {
    const float* test  = (const float*)d_in[0];
    const float* train = (const float*)d_in[1];
    float* out = (float*)d_out;

    char* ws = (char*)d_ws;
    unsigned short* Be = (unsigned short*)ws;            // 16384*128*2 = 4,194,304 B
    float* fws    = (float*)(ws + 4194304);
    float* rnorm  = fws;                 // 16384
    float* psum   = rnorm + NTRAIN;      // 16384
    float* psumsq = psum + 16384;        // 16384
    float* inv_bw = psumsq + 16384;      // 128
    float* scalars = inv_bw + 128;       // 8

    hipLaunchKernelGGL(col_stats_partial, dim3(128), dim3(256), 0, stream, train, psum, psumsq, out);
    hipLaunchKernelGGL(bandwidth_kernel, dim3(1), dim3(256), 0, stream, psum, psumsq, inv_bw, scalars);
    hipLaunchKernelGGL(expand_train, dim3(NTRAIN / 2), dim3(256), 0, stream,
                       train, inv_bw, Be, rnorm);
    hipLaunchKernelGGL(kde_main, dim3(NTEST / 64, 16), dim3(256), 0, stream,
                       test, Be, inv_bw, rnorm, scalars, out);
}

// Round 8
// 147.861 us; speedup vs baseline: 1.0458x; 1.0458x over previous
//
#include <hip/hip_runtime.h>
#include <hip/hip_bf16.h>
#include <stdint.h>

#define NTEST 4096
#define NTRAIN 16384
#define DIM 128
#define KEXP 128   // pure hi.hi bf16 (norms exact fp32)

typedef __attribute__((ext_vector_type(8))) short short8;
typedef __attribute__((ext_vector_type(16))) float float16v;

static __device__ __forceinline__ unsigned short f32_to_bf16_rne(float f) {
    union { float f; uint32_t u; } v; v.f = f;
    uint32_t u = v.u;
    uint32_t r = u + 0x7FFFu + ((u >> 16) & 1u);
    return (unsigned short)(r >> 16);
}

// ---- Kernel 1: per-column partial sums for std (coalesced) + zero out ----
__global__ void col_stats_partial(const float* __restrict__ train,
                                  float* __restrict__ psum, float* __restrict__ psumsq,
                                  float* __restrict__ out) {
    int b = blockIdx.x;       // 128 blocks x 128 rows each
    int t = threadIdx.x;      // 256
    if (b < 16) out[b * 256 + t] = 0.f;   // zero output (re-poisoned each call)
    int col = t & 127;
    int rh = t >> 7;          // 0/1
    float s = 0.f, ss = 0.f;
    int row0 = b * 128;
    for (int r = rh; r < 128; r += 2) {
        float x = train[(size_t)(row0 + r) * DIM + col];
        s += x; ss += x * x;
    }
    __shared__ float sh_s[256], sh_ss[256];
    sh_s[t] = s; sh_ss[t] = ss;
    __syncthreads();
    if (rh == 0) {
        psum[b * DIM + col]   = sh_s[col] + sh_s[col + 128];
        psumsq[b * DIM + col] = sh_ss[col] + sh_ss[col + 128];
    }
}

// ---- Kernel 2: bandwidth + Z scalars ----
__global__ void bandwidth_kernel(const float* __restrict__ psum, const float* __restrict__ psumsq,
                                 float* __restrict__ inv_bw, float* __restrict__ scalars) {
    int t = threadIdx.x;      // 256
    int c = t & 127;
    int h = t >> 7;
    float s = 0.f, ss = 0.f;
    for (int b = h * 64; b < h * 64 + 64; ++b) { s += psum[b * DIM + c]; ss += psumsq[b * DIM + c]; }
    __shared__ float S[256], SS[256], sh[128];
    S[t] = s; SS[t] = ss;
    __syncthreads();
    if (h == 0) {
        s = S[c] + S[c + 128]; ss = SS[c] + SS[c + 128];
        float n = (float)NTRAIN;
        float var = (ss - s * s / n) / (n - 1.0f);
        float sd = fmaxf(sqrtf(var), 0.01f);
        float bw = 1.06f * sd * expf(-logf(n) / (float)(4 + DIM));
        bw = fminf(bw, 0.49f);
        inv_bw[c] = 1.0f / bw;
        sh[c] = logf(bw);
    }
    __syncthreads();
    for (int off = 64; off > 0; off >>= 1) {
        if (t < off) sh[t] += sh[t + off];
        __syncthreads();
    }
    if (t == 0) {
        float Z = 0.5f * (float)DIM * logf(2.0f * 3.14159265358979323846f) + sh[0] + logf((float)NTRAIN);
        scalars[0] = -0.5f / Z;   // term = exp(scale*sq - 1)
    }
}

// ---- Kernel 3: train rows: scale, bf16 hi, exact row norms ----
__global__ void expand_train(const float* __restrict__ train, const float* __restrict__ inv_bw,
                             unsigned short* __restrict__ Be, float* __restrict__ rnorm) {
    int t = threadIdx.x;
    int r = blockIdx.x * 2 + (t >> 7);    // 0..NTRAIN-1
    int k = t & 127;
    float x = train[(size_t)r * DIM + k] * inv_bw[k];
    Be[(size_t)r * KEXP + k] = f32_to_bf16_rne(x);
    float nv = x * x;   // exact fp32 norm
    #pragma unroll
    for (int off = 32; off > 0; off >>= 1) nv += __shfl_xor(nv, off, 64);
    __shared__ float sh[4];
    if ((t & 63) == 0) sh[t >> 6] = nv;
    __syncthreads();
    if (k == 0) rnorm[r] = sh[(t >> 6)] + sh[(t >> 6) + 1];
}

// ---- Kernel 4: barrier-free stream loop, wave-private B staging ----
// Block: 64 m-rows, A LDS-resident (16 KB, swizzled). Each of 4 waves owns a
// 32-row n-subtile; B staged wave-privately (global_load_lds into the wave's
// own slice, read back only by that wave) -> NO __syncthreads in stream loop.
__global__ __launch_bounds__(256, 3) void kde_main(
    const float* __restrict__ test, const unsigned short* __restrict__ Be,
    const float* __restrict__ inv_bw, const float* __restrict__ rnorm,
    const float* __restrict__ scalars, float* __restrict__ out) {

    __shared__ __align__(16) unsigned short As[64 * 128];       // 16 KB swizzled
    __shared__ __align__(16) unsigned short Bs[2][4][2048];     // 2 bufs x 4 waves x 4 KB
    __shared__ float tn_lds[64];

    const int t = threadIdx.x;
    const int m0 = blockIdx.x * 64;      // 64 m-blocks
    const int grp = blockIdx.y;          // 16 n-groups x 8 tiles of 128
    const int wave = t >> 6;             // n-subtile owner (32 rows)
    const int lane = t & 63;
    const int col = lane & 31;           // operand row (n) / C-D col
    const int half = lane >> 5;          // k-half; C/D row-group

    // ---- wave-private stage of B segment s into buffer buf ----
    // segment s: n-tile j=s>>1, k-chunk kc=(s&1)*64. Slice: 32 rows x 64 bf16.
    // LDS slot c (0..255 chunks of 16B): r=c>>3, p=c&7 holds global chunk p^(r&7).
#define STAGE_B(s_, buf_)                                                            \
    {                                                                                \
        int jj = (s_) >> 1, kc = ((s_) & 1) * 64;                                    \
        int rowg = (grp * 8 + jj) * 128 + wave * 32;                                 \
        _Pragma("unroll")                                                            \
        for (int i = 0; i < 4; ++i) {                                                \
            int c = i * 64 + lane;                                                   \
            int r = c >> 3;                                                          \
            int p = (c & 7) ^ (r & 7);                                               \
            const unsigned short* gb = Be + (size_t)(rowg + r) * KEXP + kc + p * 8;  \
            __builtin_amdgcn_global_load_lds(                                        \
                (const __attribute__((address_space(1))) void*)gb,                   \
                (__attribute__((address_space(3))) void*)(&Bs[buf_][wave][c * 8]),   \
                16, 0, 0);                                                           \
        }                                                                            \
    }

    STAGE_B(0, 0);   // issue first (longest latency), before A-build VALU work

    // ---- build A (bf16 of test*inv_bw) swizzled in LDS + exact tnorm ----
    {
        int p = t & 15;                       // 16B chunk within row
        float4 w0 = *(const float4*)(inv_bw + p * 8);
        float4 w1 = *(const float4*)(inv_bw + p * 8 + 4);
        #pragma unroll
        for (int rr = 0; rr < 4; ++rr) {
            int row = (t >> 4) + rr * 16;     // 0..63
            const float* src = test + (size_t)(m0 + row) * DIM + p * 8;
            float4 v0 = *(const float4*)(src);
            float4 v1 = *(const float4*)(src + 4);
            v0.x *= w0.x; v0.y *= w0.y; v0.z *= w0.z; v0.w *= w0.w;
            v1.x *= w1.x; v1.y *= w1.y; v1.z *= w1.z; v1.w *= w1.w;
            short8 hv;
            hv[0] = (short)f32_to_bf16_rne(v0.x); hv[1] = (short)f32_to_bf16_rne(v0.y);
            hv[2] = (short)f32_to_bf16_rne(v0.z); hv[3] = (short)f32_to_bf16_rne(v0.w);
            hv[4] = (short)f32_to_bf16_rne(v1.x); hv[5] = (short)f32_to_bf16_rne(v1.y);
            hv[6] = (short)f32_to_bf16_rne(v1.z); hv[7] = (short)f32_to_bf16_rne(v1.w);
            int pp = p ^ (row & 7);
            *(short8*)(As + row * 128 + pp * 8) = hv;
            float nv = v0.x*v0.x + v0.y*v0.y + v0.z*v0.z + v0.w*v0.w
                     + v1.x*v1.x + v1.y*v1.y + v1.z*v1.z + v1.w*v1.w;
            #pragma unroll
            for (int off = 1; off < 16; off <<= 1) nv += __shfl_xor(nv, off, 16);
            if ((t & 15) == 0) tn_lds[row] = nv;
        }
    }
    __syncthreads();   // the ONLY block barrier: A + tnorm visible

    // folded epilogue: term = exp2( K2*d + (S1*tn + C1) + S1*rn )
    const float scale = scalars[0];
    const float L2E = 1.44269504f;
    const float S1 = scale * L2E;
    const float K2 = -2.0f * scale * L2E;
    const float C1 = -L2E;

    float pc[2][16];
    #pragma unroll
    for (int tm = 0; tm < 2; ++tm)
        #pragma unroll
        for (int g = 0; g < 16; ++g) {
            int rowi = tm * 32 + (g & 3) + 8 * (g >> 2) + 4 * half;
            pc[tm][g] = fmaf(S1, tn_lds[rowi], C1);
        }

    int abase[2], arx[2];
    #pragma unroll
    for (int tm = 0; tm < 2; ++tm) {
        int rA = tm * 32 + col;
        abase[tm] = rA * 128;
        arx[tm] = rA & 7;
    }
    const int bx = col & 7;               // B swizzle key for this lane's row

    float rs[2][16];
    #pragma unroll
    for (int tm = 0; tm < 2; ++tm)
        #pragma unroll
        for (int g = 0; g < 16; ++g) rs[tm][g] = 0.f;

    float16v acc[2];
    float pn = 0.f;

    // ---- 16 segments (8 n-tiles x 2 K-chunks), NO barriers ----
    for (int s = 0; s < 16; ++s) {
        int buf = s & 1;
        if ((s & 1) == 0) {   // new n-tile: rnorm + zero acc
            int n0j = (grp * 8 + (s >> 1)) * 128;
            pn = S1 * rnorm[n0j + wave * 32 + col];
            acc[0] = (float16v)(0.f);
            acc[1] = (float16v)(0.f);
        }
        #pragma unroll
        for (int ks = 0; ks < 4; ++ks) {
            int kta = (s & 1) * 4 + ks;       // global K chunk-pair 0..7
            short8 af0 = *(const short8*)(As + abase[0] + (((kta * 2 + half) ^ arx[0]) << 3));
            short8 af1 = *(const short8*)(As + abase[1] + (((kta * 2 + half) ^ arx[1]) << 3));
            short8 bf  = *(const short8*)(&Bs[buf][wave][(col * 8 + ((ks * 2 + half) ^ bx)) * 8]);
            acc[0] = __builtin_amdgcn_mfma_f32_32x32x16_bf16(af0, bf, acc[0], 0, 0, 0);
            acc[1] = __builtin_amdgcn_mfma_f32_32x32x16_bf16(af1, bf, acc[1], 0, 0, 0);
        }
        if (s < 15) STAGE_B(s + 1, buf ^ 1);   // issued after this segment's ds_reads
        if ((s & 1) == 1) {   // n-tile done: folded exp2 epilogue
            #pragma unroll
            for (int tm = 0; tm < 2; ++tm)
                #pragma unroll
                for (int g = 0; g < 16; ++g)
                    rs[tm][g] += exp2f(fmaf(K2, acc[tm][g], pc[tm][g] + pn));
        }
    }
#undef STAGE_B

    // ---- final: reduce across 32 cols + atomics ----
    #pragma unroll
    for (int tm = 0; tm < 2; ++tm) {
        #pragma unroll
        for (int g = 0; g < 16; ++g) {
            float v = rs[tm][g];
            #pragma unroll
            for (int off = 1; off < 32; off <<= 1)
                v += __shfl_xor(v, off, 64);   // offs 1..16: stays within 32-lane half
            if (col == 0) {
                int rowi = tm * 32 + (g & 3) + 8 * (g >> 2) + 4 * half;
                atomicAdd(&out[m0 + rowi], v);
            }
        }
    }
}

extern "C" void kernel_launch(void* const* d_in, const int* in_sizes, int n_in,
                              void* d_out, int out_size, void* d_ws, size_t ws_size,
                              hipStream_t stream) {
    const float* test  = (const float*)d_in[0];
    const float* train = (const float*)d_in[1];
    float* out = (float*)d_out;

    char* ws = (char*)d_ws;
    unsigned short* Be = (unsigned short*)ws;            // 16384*128*2 = 4,194,304 B
    float* fws    = (float*)(ws + 4194304);
    float* rnorm  = fws;                 // 16384
    float* psum   = rnorm + NTRAIN;      // 16384
    float* psumsq = psum + 16384;        // 16384
    float* inv_bw = psumsq + 16384;      // 128
    float* scalars = inv_bw + 128;       // 8

    hipLaunchKernelGGL(col_stats_partial, dim3(128), dim3(256), 0, stream, train, psum, psumsq, out);
    hipLaunchKernelGGL(bandwidth_kernel, dim3(1), dim3(256), 0, stream, psum, psumsq, inv_bw, scalars);
    hipLaunchKernelGGL(expand_train, dim3(NTRAIN / 2), dim3(256), 0, stream,
                       train, inv_bw, Be, rnorm);
    hipLaunchKernelGGL(kde_main, dim3(NTEST / 64, 16), dim3(256), 0, stream,
                       test, Be, inv_bw, rnorm, scalars, out);
}